// Round 14
// baseline (315.480 us; speedup 1.0000x reference)
//
#include <hip/hip_runtime.h>
#include <math.h>

#define T_LEN   720
#define V_DIM   64
#define KBINS   4
#define NKNOTS  4
#define BLOCK   768     // 12 waves; 16 v-groups x 48 t-phases; TSLICE uniform 15
#define TSLICE  15
#define NW      12
#define CHUNK   4       // batches per block; stages pipeline P2(b-1) with P1(b)

typedef float vfloat4 __attribute__((ext_vector_type(4)));   // native vec for nontemporal builtin

// ws float offsets (kernel A -> kernel B)
#define WS_TAB  0       // [720][8] = {cos k0..3, sin k0..3} per t
#define WS_SR   5760    // [4][64]  Re(scale)-1, [k][v]
#define WS_SI   6016    // [4][64]  Im(scale),   [k][v]
#define WS_KN   6272    // [4][64]  clipped knots, [n][v]

__device__ __forceinline__ unsigned f2bf_rne(float f) {
    unsigned u = __float_as_uint(f);
    return (u + 0x7FFFu + ((u >> 16) & 1u)) >> 16;
}

// ---- Kernel A: one-time tables (no transcendentals in kernel B) ----
__global__ __launch_bounds__(256) void precompute_kernel(
    const float* __restrict__ a, const float* __restrict__ phi,
    const float* __restrict__ env_knots, const int* __restrict__ k_bins,
    float* __restrict__ ws)
{
    int id = blockIdx.x * 256 + threadIdx.x;
    if (id < T_LEN * KBINS) {
        int t = id >> 2, k = id & 3;
        int kb = k_bins[k];
        int m  = (kb * t) % T_LEN;                       // exact integer angle reduction
        float th = (float)m * 0.00872664625997164788f;   // 2*pi/720
        float sn, cs;
        sincosf(th, &sn, &cs);
        ws[WS_TAB + t * 8 + k]     = cs;
        ws[WS_TAB + t * 8 + 4 + k] = sn;
    } else if (id < T_LEN * KBINS + V_DIM * KBINS) {
        int e = id - T_LEN * KBINS;                      // v*4+k
        int v = e >> 2, k = e & 3;
        float amp = 1.0f + a[e];
        float ph  = tanhf(phi[e]) * 0.25f;
        float sp, cp;
        sincosf(ph, &sp, &cp);
        ws[WS_SR + k * V_DIM + v] = amp * cp - 1.0f;
        ws[WS_SI + k * V_DIM + v] = amp * sp;
    } else if (id < T_LEN * KBINS + V_DIM * KBINS + V_DIM * NKNOTS) {
        int e = id - T_LEN * KBINS - V_DIM * KBINS;      // v*4+n
        int v = e >> 2, n = e & 3;
        ws[WS_KN + n * V_DIM + v] = fminf(fmaxf(env_knots[e], 0.5f), 1.5f);
    }
}

// ---- Kernel B: CHUNK-batch pipeline: stage c = P2(b_{c-1}) fused with P1(b_c) ----
// Reads+writes overlap continuously; P2 re-read is L3-hot (read one stage ago).
// LDS 51,456 B -> 2 blocks/CU target; coef packed bf16 keeps VGPR <= ~84.
__global__ __launch_bounds__(BLOCK) void SeasonalEnvelopeAdapter_kernel(
    const float* __restrict__ y,
    const float* __restrict__ ws,
    float* __restrict__ out,
    int B)
{
    __shared__ __align__(16) float tab[T_LEN * 8];       // 23,040 B {c0..3,s0..3}/t
    __shared__ float red[16][NW][33];                    // 25,344 B fixed-order reduce
    __shared__ __align__(16) float coefT[8][V_DIM];      //  2,048 B [k][v] re / [4+k][v] im
    __shared__ __align__(16) float knT[NKNOTS][V_DIM];   //  1,024 B

    const int tid  = threadIdx.x;
    const int g    = tid & 15;      // v-group: v0 = 4*g -> 256 B/row coalesced
    const int s    = tid >> 4;      // t-phase 0..47; t = 48*i + s
    const int lane = tid & 63;
    const int w    = tid >> 6;      // wave 0..11

    // ---- Phase 0: ws tables -> LDS ----
    for (int e = tid; e < 1440; e += BLOCK)
        ((float4*)tab)[e] = ((const float4*)(ws + WS_TAB))[e];
    if (tid < NKNOTS * V_DIM) ((float*)knT)[tid] = ws[WS_KN + tid];
    __syncthreads();

    const int b0 = blockIdx.x * CHUNK;
    const float posScale = 3.0f / 719.0f;
    float accre[4][4], accim[4][4];

    #pragma unroll 1
    for (int c = 0; c <= CHUNK; ++c) {
        const int bP1 = b0 + c;
        const int bP2 = b0 + c - 1;
        const bool doP1 = (c < CHUNK) && (bP1 < B);
        const bool doP2 = (c > 0) && (bP2 < B);

        const size_t base1 = (size_t)bP1 * (T_LEN * V_DIM) + (size_t)(g << 2);
        const size_t base2 = (size_t)bP2 * (T_LEN * V_DIM) + (size_t)(g << 2);

        // coef of bP2 (written last stage) -> packed bf16 registers (16 uints)
        unsigned cre01[4], cre23[4], cim01[4], cim23[4];
        if (doP2) {
            #pragma unroll
            for (int k = 0; k < 4; ++k) {
                float4 r4 = *(const float4*)(&coefT[k][g << 2]);
                float4 i4 = *(const float4*)(&coefT[4 + k][g << 2]);
                cre01[k] = f2bf_rne(r4.x) | (f2bf_rne(r4.y) << 16);
                cre23[k] = f2bf_rne(r4.z) | (f2bf_rne(r4.w) << 16);
                cim01[k] = f2bf_rne(i4.x) | (f2bf_rne(i4.y) << 16);
                cim23[k] = f2bf_rne(i4.z) | (f2bf_rne(i4.w) << 16);
            }
        }
        if (doP1) {
            #pragma unroll
            for (int j = 0; j < 4; ++j)
                #pragma unroll
                for (int k = 0; k < 4; ++k) { accre[j][k] = 0.f; accim[j][k] = 0.f; }
        }

        float4 yv[2], zv[2];
        if (doP1) {
            yv[0] = *(const float4*)(y + base1 + (size_t)s * V_DIM);
            yv[1] = *(const float4*)(y + base1 + (size_t)(48 + s) * V_DIM);
        }
        if (doP2) {
            zv[0] = *(const float4*)(y + base2 + (size_t)s * V_DIM);
            zv[1] = *(const float4*)(y + base2 + (size_t)(48 + s) * V_DIM);
        }

        #pragma unroll
        for (int i = 0; i < TSLICE; ++i) {
            const int t = 48 * i + s;
            float4 c4 = *(const float4*)(&tab[t * 8]);
            float4 s4 = *(const float4*)(&tab[t * 8 + 4]);
            const float cs[4] = {c4.x, c4.y, c4.z, c4.w};
            const float sn[4] = {s4.x, s4.y, s4.z, s4.w};

            if (doP1) {   // DFT-accumulate new batch
                float4 cur = yv[i & 1];
                if (i + 2 < TSLICE)
                    yv[i & 1] = *(const float4*)(y + base1 + (size_t)(48 * (i + 2) + s) * V_DIM);
                const float yj[4] = {cur.x, cur.y, cur.z, cur.w};
                #pragma unroll
                for (int j = 0; j < 4; ++j)
                    #pragma unroll
                    for (int k = 0; k < 4; ++k) {
                        accre[j][k] = fmaf(yj[j], cs[k], accre[j][k]);
                        accim[j][k] = fmaf(yj[j], sn[k], accim[j][k]);
                    }
            }
            if (doP2) {   // reconstruct + envelope previous batch (L3-hot re-read)
                float4 cur = zv[i & 1];
                if (i + 2 < TSLICE)
                    zv[i & 1] = *(const float4*)(y + base2 + (size_t)(48 * (i + 2) + s) * V_DIM);
                float d0 = 0.f, d1 = 0.f, d2 = 0.f, d3 = 0.f;
                #pragma unroll
                for (int k = 0; k < 4; ++k) {
                    float ck = cs[k], sk = sn[k];
                    float r0 = __uint_as_float(cre01[k] << 16);
                    float r1 = __uint_as_float(cre01[k] & 0xFFFF0000u);
                    float r2 = __uint_as_float(cre23[k] << 16);
                    float r3 = __uint_as_float(cre23[k] & 0xFFFF0000u);
                    float i0 = __uint_as_float(cim01[k] << 16);
                    float i1 = __uint_as_float(cim01[k] & 0xFFFF0000u);
                    float i2 = __uint_as_float(cim23[k] << 16);
                    float i3 = __uint_as_float(cim23[k] & 0xFFFF0000u);
                    d0 = fmaf(r0, ck, fmaf(-i0, sk, d0));
                    d1 = fmaf(r1, ck, fmaf(-i1, sk, d1));
                    d2 = fmaf(r2, ck, fmaf(-i2, sk, d2));
                    d3 = fmaf(r3, ck, fmaf(-i3, sk, d3));
                }
                float pos = (float)t * posScale;
                int idx = (int)pos; idx = idx > 2 ? 2 : idx;
                float frac = pos - (float)idx;
                float4 e0v = *(const float4*)(&knT[idx][g << 2]);
                float4 e1v = *(const float4*)(&knT[idx + 1][g << 2]);
                vfloat4 o;
                o.x = (cur.x + d0) * fmaf(e1v.x - e0v.x, frac, e0v.x);
                o.y = (cur.y + d1) * fmaf(e1v.y - e0v.y, frac, e0v.y);
                o.z = (cur.z + d2) * fmaf(e1v.z - e0v.z, frac, e0v.z);
                o.w = (cur.w + d3) * fmaf(e1v.w - e0v.w, frac, e0v.w);
                __builtin_nontemporal_store(o, (vfloat4*)(out + base2 + (size_t)t * V_DIM));
            }
        }

        if (doP1) {   // wave shuffle-reduce + per-wave partials
            #pragma unroll
            for (int j = 0; j < 4; ++j)
                #pragma unroll
                for (int k = 0; k < 4; ++k) {
                    float r = accre[j][k], im = accim[j][k];
                    r  += __shfl_xor(r, 16, 64);  r  += __shfl_xor(r, 32, 64);
                    im += __shfl_xor(im, 16, 64); im += __shfl_xor(im, 32, 64);
                    accre[j][k] = r; accim[j][k] = im;
                }
            if (lane < 16) {   // lane == g
                #pragma unroll
                for (int j = 0; j < 4; ++j)
                    #pragma unroll
                    for (int k = 0; k < 4; ++k) {
                        red[lane][w][j * 8 + k]     = accre[j][k];
                        red[lane][w][j * 8 + 4 + k] = accim[j][k];
                    }
            }
        }
        __syncthreads();   // P2 coefT reads done; red complete
        if (doP1 && tid < 256) {   // fixed-order sum + (scale-1) -> coefT (deterministic)
            int v = tid >> 2, k = tid & 3;
            int gg = v >> 2, j = v & 3;
            float cr = 0.f, ci = 0.f;
            #pragma unroll
            for (int ww = 0; ww < NW; ++ww) {
                cr += red[gg][ww][j * 8 + k];
                ci += red[gg][ww][j * 8 + 4 + k];
            }
            float sr = ws[WS_SR + k * V_DIM + v];
            float si = ws[WS_SI + k * V_DIM + v];
            const float sc = 2.0f / (float)T_LEN;
            coefT[k][v]     = (cr * sr + ci * si) * sc;   // Re C * 2/T
            coefT[4 + k][v] = (cr * si - ci * sr) * sc;   // Im C * 2/T
        }
        __syncthreads();   // coefT(bP1) ready for next stage
    }
}

extern "C" void kernel_launch(void* const* d_in, const int* in_sizes, int n_in,
                              void* d_out, int out_size, void* d_ws, size_t ws_size,
                              hipStream_t stream) {
    const float* y         = (const float*)d_in[0];
    const float* a         = (const float*)d_in[1];
    const float* phi       = (const float*)d_in[2];
    const float* env_knots = (const float*)d_in[3];
    const int*   k_bins    = (const int*)d_in[4];
    float* out = (float*)d_out;
    float* ws  = (float*)d_ws;

    int B = in_sizes[0] / (T_LEN * V_DIM);
    int ids = T_LEN * KBINS + V_DIM * KBINS + V_DIM * NKNOTS;
    precompute_kernel<<<(ids + 255) / 256, 256, 0, stream>>>(a, phi, env_knots, k_bins, ws);
    int grid = (B + CHUNK - 1) / CHUNK;
    SeasonalEnvelopeAdapter_kernel<<<grid, BLOCK, 0, stream>>>(y, ws, out, B);
}

// Round 15
// 281.263 us; speedup vs baseline: 1.1217x; 1.1217x over previous
//
#include <hip/hip_runtime.h>
#include <math.h>

#define T_LEN   720
#define V_DIM   64
#define KBINS   4
#define NKNOTS  4
#define BLOCK   768     // 12 waves: 6 producer + 6 consumer
#define TSLICE  15      // per role: 8 v-groups x 48 t-phases, t = 48i+s
#define VB      32      // v's per block (half); 2 blocks cover a batch
#define NPW     6       // producer waves
#define CHUNK   16      // batches per block -> grid = 2 * B/CHUNK = 256 (persistent)
#define PIPE    5       // producer global-load depth
#define YSU     17      // ystash row stride in uints (68 B -> bank-spread)

// ws float offsets (kernel A -> kernel B)
#define WS_TAB  0       // [720][8] = {cos k0..3, sin k0..3} per t
#define WS_SR   5760    // [4][64]  Re(scale)-1, [k][v]
#define WS_SI   6016    // [4][64]  Im(scale),   [k][v]
#define WS_KN   6272    // [4][64]  clipped knots, [n][v]

__device__ __forceinline__ unsigned f2bf_rne(float f) {
    unsigned u = __float_as_uint(f);
    return (u + 0x7FFFu + ((u >> 16) & 1u)) >> 16;
}
__device__ __forceinline__ float bf2f(unsigned h) {
    return __uint_as_float(h << 16);
}

// ---- Kernel A: one-time tables (no transcendentals in kernel B) ----
__global__ __launch_bounds__(256) void precompute_kernel(
    const float* __restrict__ a, const float* __restrict__ phi,
    const float* __restrict__ env_knots, const int* __restrict__ k_bins,
    float* __restrict__ ws)
{
    int id = blockIdx.x * 256 + threadIdx.x;
    if (id < T_LEN * KBINS) {
        int t = id >> 2, k = id & 3;
        int kb = k_bins[k];
        int m  = (kb * t) % T_LEN;                       // exact integer angle reduction
        float th = (float)m * 0.00872664625997164788f;   // 2*pi/720
        float sn, cs;
        sincosf(th, &sn, &cs);
        ws[WS_TAB + t * 8 + k]     = cs;
        ws[WS_TAB + t * 8 + 4 + k] = sn;
    } else if (id < T_LEN * KBINS + V_DIM * KBINS) {
        int e = id - T_LEN * KBINS;                      // v*4+k
        int v = e >> 2, k = e & 3;
        float amp = 1.0f + a[e];
        float ph  = tanhf(phi[e]) * 0.25f;
        float sp, cp;
        sincosf(ph, &sp, &cp);
        ws[WS_SR + k * V_DIM + v] = amp * cp - 1.0f;
        ws[WS_SI + k * V_DIM + v] = amp * sp;
    } else if (id < T_LEN * KBINS + V_DIM * KBINS + V_DIM * NKNOTS) {
        int e = id - T_LEN * KBINS - V_DIM * KBINS;      // v*4+n
        int v = e >> 2, n = e & 3;
        ws[WS_KN + n * V_DIM + v] = fminf(fmaxf(env_knots[e], 0.5f), 1.5f);
    }
}

// ---- Kernel B: wave-specialized producer/consumer pipeline over CHUNK batches ----
// Waves 0-5 DFT batch c (HBM reads -> LDS bf16 stash); waves 6-11 reconstruct
// batch c-1 from the other LDS buffer (stores). Reads+writes stream concurrently.
// LDS 129,856 B -> 1 block/CU, persistent grid of 256.
__global__ __launch_bounds__(BLOCK) void SeasonalEnvelopeAdapter_kernel(
    const float* __restrict__ y,
    const float* __restrict__ ws,
    float* __restrict__ out,
    int B)
{
    __shared__ __align__(16) float tab[T_LEN * 8];       // 23,040 B {c0..3,s0..3}/t
    __shared__ unsigned ystash[2][T_LEN][YSU];           // 97,920 B bf16 y, dbuf
    __shared__ float red[8][NPW][33];                    //  6,336 B
    __shared__ __align__(16) float coefT[2][8][VB];      //  2,048 B dbuf [k][vl] re / [4+k][vl] im
    __shared__ __align__(16) float knT[NKNOTS][VB];      //    512 B

    const int tid  = threadIdx.x;
    const int w    = tid >> 6;                  // wave 0..11
    const bool isProd = (w < NPW);
    const int rt   = isProd ? tid : tid - NPW * 64;   // role-local 0..383
    const int g    = rt & 7;                    // v-group: vl = 4g
    const int sph  = rt >> 3;                   // t-phase 0..47
    const int lane = tid & 63;

    const int h     = blockIdx.x & 1;
    const int b0    = (blockIdx.x >> 1) * CHUNK;
    const int vbase = h * VB;

    // ---- one-time: tables -> LDS ----
    for (int e = tid; e < 1440; e += BLOCK)
        ((float4*)tab)[e] = ((const float4*)(ws + WS_TAB))[e];
    if (tid < NKNOTS * VB) {
        int n = tid >> 5, vl = tid & 31;
        knT[n][vl] = ws[WS_KN + n * V_DIM + vbase + vl];
    }
    __syncthreads();

    const float posScale = 3.0f / 719.0f;

    #pragma unroll 1
    for (int c = 0; c <= CHUNK; ++c) {
        const int pbuf = c & 1, cbuf = pbuf ^ 1;
        const int bP = b0 + c, bC = b0 + c - 1;
        const bool doProd = (c < CHUNK) && (bP < B);
        const bool doCons = (c > 0) && (bC < B);

        if (isProd) {
            if (doProd) {   // ---- producer: stream y, DFT, stash bf16 ----
                const size_t base = (size_t)bP * (T_LEN * V_DIM) + (size_t)(vbase + (g << 2));
                float accre[4][4], accim[4][4];
                #pragma unroll
                for (int j = 0; j < 4; ++j)
                    #pragma unroll
                    for (int k = 0; k < 4; ++k) { accre[j][k] = 0.f; accim[j][k] = 0.f; }
                float4 yv[PIPE];
                #pragma unroll
                for (int i0 = 0; i0 < PIPE; ++i0)
                    yv[i0] = *(const float4*)(y + base + (size_t)(48 * i0 + sph) * V_DIM);
                #pragma unroll
                for (int i = 0; i < TSLICE; ++i) {
                    const int t = 48 * i + sph;
                    float4 cur = yv[i % PIPE];
                    if (i + PIPE < TSLICE)
                        yv[i % PIPE] = *(const float4*)(y + base + (size_t)(48 * (i + PIPE) + sph) * V_DIM);
                    ystash[pbuf][t][(g << 1)]     = f2bf_rne(cur.x) | (f2bf_rne(cur.y) << 16);
                    ystash[pbuf][t][(g << 1) + 1] = f2bf_rne(cur.z) | (f2bf_rne(cur.w) << 16);
                    float4 c4 = *(const float4*)(&tab[t * 8]);
                    float4 s4 = *(const float4*)(&tab[t * 8 + 4]);
                    const float cs[4] = {c4.x, c4.y, c4.z, c4.w};
                    const float sn[4] = {s4.x, s4.y, s4.z, s4.w};
                    const float yj[4] = {cur.x, cur.y, cur.z, cur.w};
                    #pragma unroll
                    for (int j = 0; j < 4; ++j)
                        #pragma unroll
                        for (int k = 0; k < 4; ++k) {
                            accre[j][k] = fmaf(yj[j], cs[k], accre[j][k]);
                            accim[j][k] = fmaf(yj[j], sn[k], accim[j][k]);
                        }
                }
                // reduce over the wave's 8 s-phases (same-g lanes differ by 8/16/32)
                #pragma unroll
                for (int j = 0; j < 4; ++j)
                    #pragma unroll
                    for (int k = 0; k < 4; ++k) {
                        float r = accre[j][k], im = accim[j][k];
                        r  += __shfl_xor(r, 8, 64);  r  += __shfl_xor(r, 16, 64);  r  += __shfl_xor(r, 32, 64);
                        im += __shfl_xor(im, 8, 64); im += __shfl_xor(im, 16, 64); im += __shfl_xor(im, 32, 64);
                        accre[j][k] = r; accim[j][k] = im;
                    }
                if (lane < 8) {   // lane == g
                    #pragma unroll
                    for (int j = 0; j < 4; ++j)
                        #pragma unroll
                        for (int k = 0; k < 4; ++k) {
                            red[lane][w][j * 8 + k]     = accre[j][k];
                            red[lane][w][j * 8 + 4 + k] = accim[j][k];
                        }
                }
            }
        } else {
            if (doCons) {   // ---- consumer: reconstruct from LDS bf16 + envelope, store ----
                const size_t base = (size_t)bC * (T_LEN * V_DIM) + (size_t)(vbase + (g << 2));
                float cre[4][4], cim[4][4];   // [k][j]
                #pragma unroll
                for (int k = 0; k < 4; ++k) {
                    float4 r4 = *(const float4*)(&coefT[cbuf][k][g << 2]);
                    float4 i4 = *(const float4*)(&coefT[cbuf][4 + k][g << 2]);
                    cre[k][0] = r4.x; cre[k][1] = r4.y; cre[k][2] = r4.z; cre[k][3] = r4.w;
                    cim[k][0] = i4.x; cim[k][1] = i4.y; cim[k][2] = i4.z; cim[k][3] = i4.w;
                }
                #pragma unroll
                for (int i = 0; i < TSLICE; ++i) {
                    const int t = 48 * i + sph;
                    unsigned p0 = ystash[cbuf][t][(g << 1)];
                    unsigned p1 = ystash[cbuf][t][(g << 1) + 1];
                    const float yj[4] = { bf2f(p0 & 0xFFFFu), bf2f(p0 >> 16),
                                          bf2f(p1 & 0xFFFFu), bf2f(p1 >> 16) };
                    float4 c4 = *(const float4*)(&tab[t * 8]);
                    float4 s4 = *(const float4*)(&tab[t * 8 + 4]);
                    const float cs[4] = {c4.x, c4.y, c4.z, c4.w};
                    const float sn[4] = {s4.x, s4.y, s4.z, s4.w};
                    float pos = (float)t * posScale;
                    int idx = (int)pos; idx = idx > 2 ? 2 : idx;
                    float frac = pos - (float)idx;
                    float4 e0v = *(const float4*)(&knT[idx][g << 2]);
                    float4 e1v = *(const float4*)(&knT[idx + 1][g << 2]);
                    const float e0[4] = {e0v.x, e0v.y, e0v.z, e0v.w};
                    const float e1[4] = {e1v.x, e1v.y, e1v.z, e1v.w};
                    float oj[4];
                    #pragma unroll
                    for (int j = 0; j < 4; ++j) {
                        float d = 0.f;
                        #pragma unroll
                        for (int k = 0; k < 4; ++k)
                            d = fmaf(cre[k][j], cs[k], fmaf(-cim[k][j], sn[k], d));
                        float env = fmaf(e1[j] - e0[j], frac, e0[j]);
                        oj[j] = (yj[j] + d) * env;
                    }
                    float4 o; o.x = oj[0]; o.y = oj[1]; o.z = oj[2]; o.w = oj[3];
                    *(float4*)(out + base + (size_t)t * V_DIM) = o;
                }
            }
        }
        __syncthreads();   // producers' red + stash complete; consumers done with cbuf
        if (doProd && tid < 128) {   // fixed-order sum + (scale-1) -> coefT[pbuf]
            int vl = tid >> 2, k = tid & 3;
            int gg = vl >> 2, j = vl & 3;
            float cr = 0.f, ci = 0.f;
            #pragma unroll
            for (int ww = 0; ww < NPW; ++ww) {
                cr += red[gg][ww][j * 8 + k];
                ci += red[gg][ww][j * 8 + 4 + k];
            }
            int v = vbase + vl;
            float sr = ws[WS_SR + k * V_DIM + v];
            float si = ws[WS_SI + k * V_DIM + v];
            const float sc = 2.0f / (float)T_LEN;
            coefT[pbuf][k][vl]     = (cr * sr + ci * si) * sc;   // Re C * 2/T
            coefT[pbuf][4 + k][vl] = (cr * si - ci * sr) * sc;   // Im C * 2/T
        }
        __syncthreads();   // coefT[pbuf] ready for next stage's consumers
    }
}

extern "C" void kernel_launch(void* const* d_in, const int* in_sizes, int n_in,
                              void* d_out, int out_size, void* d_ws, size_t ws_size,
                              hipStream_t stream) {
    const float* y         = (const float*)d_in[0];
    const float* a         = (const float*)d_in[1];
    const float* phi       = (const float*)d_in[2];
    const float* env_knots = (const float*)d_in[3];
    const int*   k_bins    = (const int*)d_in[4];
    float* out = (float*)d_out;
    float* ws  = (float*)d_ws;

    int B = in_sizes[0] / (T_LEN * V_DIM);
    int ids = T_LEN * KBINS + V_DIM * KBINS + V_DIM * NKNOTS;
    precompute_kernel<<<(ids + 255) / 256, 256, 0, stream>>>(a, phi, env_knots, k_bins, ws);
    int grid = 2 * ((B + CHUNK - 1) / CHUNK);
    SeasonalEnvelopeAdapter_kernel<<<grid, BLOCK, 0, stream>>>(y, ws, out, B);
}

// Round 16
// 221.874 us; speedup vs baseline: 1.4219x; 1.2677x over previous
//
#include <hip/hip_runtime.h>
#include <math.h>

#define T_LEN   720
#define V_DIM   64
#define KBINS   4
#define NKNOTS  4
#define BLOCK   768     // 12 waves; 16 v-groups x 48 t-phases; TSLICE uniform 15
#define TSLICE  15
#define NW      12
#define CHUNK   8       // batches per block; P1(c+1) loads issued during P2(c)
#define P1P     4       // HBM read pipe depth (batch c)
#define P2P     3       // L3 re-read pipe depth

typedef float vfloat4 __attribute__((ext_vector_type(4)));

// ws float offsets (kernel A -> kernel B)
#define WS_TAB  0       // [720][8] = {cos k0..3, sin k0..3} per t
#define WS_SR   5760    // [4][64]  Re(scale)-1, [k][v]
#define WS_SI   6016    // [4][64]  Im(scale),   [k][v]
#define WS_KN   6272    // [4][64]  clipped knots, [n][v]

// ---- Kernel A: one-time tables (no transcendentals in kernel B) ----
__global__ __launch_bounds__(256) void precompute_kernel(
    const float* __restrict__ a, const float* __restrict__ phi,
    const float* __restrict__ env_knots, const int* __restrict__ k_bins,
    float* __restrict__ ws)
{
    int id = blockIdx.x * 256 + threadIdx.x;
    if (id < T_LEN * KBINS) {
        int t = id >> 2, k = id & 3;
        int kb = k_bins[k];
        int m  = (kb * t) % T_LEN;                       // exact integer angle reduction
        float th = (float)m * 0.00872664625997164788f;   // 2*pi/720
        float sn, cs;
        sincosf(th, &sn, &cs);
        ws[WS_TAB + t * 8 + k]     = cs;
        ws[WS_TAB + t * 8 + 4 + k] = sn;
    } else if (id < T_LEN * KBINS + V_DIM * KBINS) {
        int e = id - T_LEN * KBINS;                      // v*4+k
        int v = e >> 2, k = e & 3;
        float amp = 1.0f + a[e];
        float ph  = tanhf(phi[e]) * 0.25f;
        float sp, cp;
        sincosf(ph, &sp, &cp);
        ws[WS_SR + k * V_DIM + v] = amp * cp - 1.0f;
        ws[WS_SI + k * V_DIM + v] = amp * sp;
    } else if (id < T_LEN * KBINS + V_DIM * KBINS + V_DIM * NKNOTS) {
        int e = id - T_LEN * KBINS - V_DIM * KBINS;      // v*4+n
        int v = e >> 2, n = e & 3;
        ws[WS_KN + n * V_DIM + v] = fminf(fmaxf(env_knots[e], 0.5f), 1.5f);
    }
}

// ---- Kernel B: per-block loop over CHUNK batches; cross-batch load/store overlap ----
// No barrier between P2(c) and P1(c+1): next-batch HBM loads are issued inside
// P2's store loop, so reads stream while stores drain. P2 re-reads y from L3
// (R7 measured FETCH = input exactly -> fully absorbed). Lean per-phase bodies.
__global__ __launch_bounds__(BLOCK) void SeasonalEnvelopeAdapter_kernel(
    const float* __restrict__ y,
    const float* __restrict__ ws,
    float* __restrict__ out,
    int B)
{
    __shared__ __align__(16) float tab[T_LEN * 8];       // 23,040 B {c0..3,s0..3}/t
    __shared__ float red[16][NW][33];                    // 25,344 B fixed-order reduce
    __shared__ __align__(16) float coefT[8][V_DIM];      //  2,048 B [k][v] re / [4+k][v] im
    __shared__ __align__(16) float knT[NKNOTS][V_DIM];   //  1,024 B
    // total 51,456 B

    const int tid  = threadIdx.x;
    const int g    = tid & 15;      // v-group: v0 = 4*g -> 256 B/row coalesced
    const int s    = tid >> 4;      // t-phase 0..47; t = 48*i + s
    const int lane = tid & 63;
    const int w    = tid >> 6;      // wave 0..11

    // ---- one-time: ws tables -> LDS ----
    for (int e = tid; e < 1440; e += BLOCK)
        ((float4*)tab)[e] = ((const float4*)(ws + WS_TAB))[e];
    if (tid < NKNOTS * V_DIM) ((float*)knT)[tid] = ws[WS_KN + tid];
    __syncthreads();

    const int b0 = blockIdx.x * CHUNK;
    const size_t vg = (size_t)(g << 2);
    const float posScale = 3.0f / 719.0f;

    float4 yv[P1P];   // persistent HBM read pipe; filled for c=0 here, for c+1 inside P2(c)
    if (b0 < B) {
        const size_t base0 = (size_t)b0 * (T_LEN * V_DIM) + vg;
        #pragma unroll
        for (int i0 = 0; i0 < P1P; ++i0)
            yv[i0] = *(const float4*)(y + base0 + (size_t)(48 * i0 + s) * V_DIM);
    }

    #pragma unroll 1
    for (int c = 0; c < CHUNK; ++c) {
        const int b = b0 + c;
        if (b >= B) break;   // block-uniform
        const size_t base  = (size_t)b * (T_LEN * V_DIM) + vg;
        const bool pf = (c + 1 < CHUNK) && (b + 1 < B);
        const size_t baseN = (size_t)(b + 1) * (T_LEN * V_DIM) + vg;

        // ---- P1: consume rolling HBM pipe, accumulate DFT partials ----
        float accre[4][4], accim[4][4];
        #pragma unroll
        for (int j = 0; j < 4; ++j)
            #pragma unroll
            for (int k = 0; k < 4; ++k) { accre[j][k] = 0.f; accim[j][k] = 0.f; }

        #pragma unroll
        for (int i = 0; i < TSLICE; ++i) {
            const int t = 48 * i + s;
            float4 cur = yv[i & 3];
            if (i + P1P < TSLICE)
                yv[i & 3] = *(const float4*)(y + base + (size_t)(48 * (i + P1P) + s) * V_DIM);
            float4 c4 = *(const float4*)(&tab[t * 8]);
            float4 s4 = *(const float4*)(&tab[t * 8 + 4]);
            const float cs[4] = {c4.x, c4.y, c4.z, c4.w};
            const float sn[4] = {s4.x, s4.y, s4.z, s4.w};
            const float yj[4] = {cur.x, cur.y, cur.z, cur.w};
            #pragma unroll
            for (int j = 0; j < 4; ++j)
                #pragma unroll
                for (int k = 0; k < 4; ++k) {
                    accre[j][k] = fmaf(yj[j], cs[k], accre[j][k]);
                    accim[j][k] = fmaf(yj[j], sn[k], accim[j][k]);
                }
        }

        // ---- reduce: shuffle over the wave's 4 s-phases, per-wave partials ----
        #pragma unroll
        for (int j = 0; j < 4; ++j)
            #pragma unroll
            for (int k = 0; k < 4; ++k) {
                float r = accre[j][k], im = accim[j][k];
                r  += __shfl_xor(r, 16, 64);  r  += __shfl_xor(r, 32, 64);
                im += __shfl_xor(im, 16, 64); im += __shfl_xor(im, 32, 64);
                accre[j][k] = r; accim[j][k] = im;
            }
        if (lane < 16) {   // lane == g
            #pragma unroll
            for (int j = 0; j < 4; ++j)
                #pragma unroll
                for (int k = 0; k < 4; ++k) {
                    red[lane][w][j * 8 + k]     = accre[j][k];
                    red[lane][w][j * 8 + 4 + k] = accim[j][k];
                }
        }
        __syncthreads();
        if (tid < 256) {   // fixed-order sum + (scale-1) -> coefT (deterministic)
            int v = tid >> 2, k = tid & 3;
            int gg = v >> 2, j = v & 3;
            float cr = 0.f, ci = 0.f;
            #pragma unroll
            for (int ww = 0; ww < NW; ++ww) {
                cr += red[gg][ww][j * 8 + k];
                ci += red[gg][ww][j * 8 + 4 + k];
            }
            float sr = ws[WS_SR + k * V_DIM + v];
            float si = ws[WS_SI + k * V_DIM + v];
            const float sc = 2.0f / (float)T_LEN;
            coefT[k][v]     = (cr * sr + ci * si) * sc;   // Re C * 2/T
            coefT[4 + k][v] = (cr * si - ci * sr) * sc;   // Im C * 2/T
        }
        __syncthreads();

        // ---- P2: L3 re-read + reconstruct + NT store; prefetch batch c+1 ----
        float cre[4][4], cim[4][4];   // [k][j]
        #pragma unroll
        for (int k = 0; k < 4; ++k) {
            float4 r4 = *(const float4*)(&coefT[k][g << 2]);
            float4 i4 = *(const float4*)(&coefT[4 + k][g << 2]);
            cre[k][0] = r4.x; cre[k][1] = r4.y; cre[k][2] = r4.z; cre[k][3] = r4.w;
            cim[k][0] = i4.x; cim[k][1] = i4.y; cim[k][2] = i4.z; cim[k][3] = i4.w;
        }
        float4 zv[P2P];
        #pragma unroll
        for (int i0 = 0; i0 < P2P; ++i0)
            zv[i0] = *(const float4*)(y + base + (size_t)(48 * i0 + s) * V_DIM);

        #pragma unroll
        for (int i = 0; i < TSLICE; ++i) {
            const int t = 48 * i + s;
            if (pf && i < P1P)   // issue next batch's HBM loads under the store stream
                yv[i] = *(const float4*)(y + baseN + (size_t)(48 * i + s) * V_DIM);
            float4 cur = zv[i % P2P];
            if (i + P2P < TSLICE)
                zv[i % P2P] = *(const float4*)(y + base + (size_t)(48 * (i + P2P) + s) * V_DIM);
            float4 c4 = *(const float4*)(&tab[t * 8]);
            float4 s4 = *(const float4*)(&tab[t * 8 + 4]);
            const float cs[4] = {c4.x, c4.y, c4.z, c4.w};
            const float sn[4] = {s4.x, s4.y, s4.z, s4.w};
            float pos = (float)t * posScale;
            int idx = (int)pos; idx = idx > 2 ? 2 : idx;
            float frac = pos - (float)idx;
            float4 e0v = *(const float4*)(&knT[idx][g << 2]);
            float4 e1v = *(const float4*)(&knT[idx + 1][g << 2]);
            const float e0[4] = {e0v.x, e0v.y, e0v.z, e0v.w};
            const float e1[4] = {e1v.x, e1v.y, e1v.z, e1v.w};
            const float yj[4] = {cur.x, cur.y, cur.z, cur.w};
            vfloat4 o;
            #pragma unroll
            for (int j = 0; j < 4; ++j) {
                float d = 0.f;
                #pragma unroll
                for (int k = 0; k < 4; ++k)
                    d = fmaf(cre[k][j], cs[k], fmaf(-cim[k][j], sn[k], d));
                float env = fmaf(e1[j] - e0[j], frac, e0[j]);
                o[j] = (yj[j] + d) * env;
            }
            __builtin_nontemporal_store(o, (vfloat4*)(out + base + (size_t)t * V_DIM));
        }
    }
}

extern "C" void kernel_launch(void* const* d_in, const int* in_sizes, int n_in,
                              void* d_out, int out_size, void* d_ws, size_t ws_size,
                              hipStream_t stream) {
    const float* y         = (const float*)d_in[0];
    const float* a         = (const float*)d_in[1];
    const float* phi       = (const float*)d_in[2];
    const float* env_knots = (const float*)d_in[3];
    const int*   k_bins    = (const int*)d_in[4];
    float* out = (float*)d_out;
    float* ws  = (float*)d_ws;

    int B = in_sizes[0] / (T_LEN * V_DIM);
    int ids = T_LEN * KBINS + V_DIM * KBINS + V_DIM * NKNOTS;
    precompute_kernel<<<(ids + 255) / 256, 256, 0, stream>>>(a, phi, env_knots, k_bins, ws);
    int grid = (B + CHUNK - 1) / CHUNK;
    SeasonalEnvelopeAdapter_kernel<<<grid, BLOCK, 0, stream>>>(y, ws, out, B);
}